// Round 2
// baseline (486.085 us; speedup 1.0000x reference)
//
#include <hip/hip_runtime.h>

typedef unsigned int u32;
typedef unsigned short u16;
typedef __bf16 bf16x8 __attribute__((ext_vector_type(8)));
typedef float f32x4 __attribute__((ext_vector_type(4)));

#define D 2048           // D_IN == D_MODEL == S == 2048
#define BATCH 2
#define SPLITK 4
#define KSLICE (D / SPLITK)  // 512 -> 16 BK=32 iterations per block

// ---------- helpers ----------
__device__ __forceinline__ u32 bf16rne(float f) {
  u32 u = __builtin_bit_cast(u32, f);
  return (u + 0x7fffu + ((u >> 16) & 1u)) >> 16;
}
__device__ __forceinline__ u32 pk2(float lo, float hi) {
  return bf16rne(lo) | (bf16rne(hi) << 16);
}
__device__ __forceinline__ void async16(const u16* g, u16* l) {
  __builtin_amdgcn_global_load_lds(
      (const __attribute__((address_space(1))) void*)g,
      (__attribute__((address_space(3))) void*)l, 16, 0, 0);
}

// ---------- kernel 1: x fp32 -> bf16 ----------
__global__ void __launch_bounds__(256) prep_x_kernel(const float* __restrict__ x,
                                                     u16* __restrict__ o) {
  size_t t = (size_t)blockIdx.x * 256 + threadIdx.x;
  const float4* x4 = (const float4*)x;
  float4 a = x4[2 * t], b = x4[2 * t + 1];
  ((uint4*)o)[t] = make_uint4(pk2(a.x, a.y), pk2(a.z, a.w),
                              pk2(b.x, b.y), pk2(b.z, b.w));
}

// ---------- kernel 2: wt[b][n][k] = bf16(p0*W[i0][k][n] + p1*W[i1][k][n]) ----------
__global__ void __launch_bounds__(256) prep_w_kernel(const float* __restrict__ W,
                                                     const int* __restrict__ sidx,
                                                     const float* __restrict__ sprob,
                                                     u16* __restrict__ wt) {
  const int b = blockIdx.z;
  const int n = blockIdx.x * 256 + threadIdx.x;
  const int k0 = blockIdx.y * 32;
  const int i0 = sidx[2 * b], i1 = sidx[2 * b + 1];
  const float p0 = sprob[2 * b], p1 = sprob[2 * b + 1];
  const float* w0 = W + ((size_t)i0 * D + k0) * D + n;
  const float* w1 = W + ((size_t)i1 * D + k0) * D + n;
  u32 r[16];
#pragma unroll
  for (int kk = 0; kk < 16; ++kk) {
    float a0 = w0[(size_t)(2 * kk) * D],     c0 = w1[(size_t)(2 * kk) * D];
    float a1 = w0[(size_t)(2 * kk + 1) * D], c1 = w1[(size_t)(2 * kk + 1) * D];
    r[kk] = pk2(p0 * a0 + p1 * c0, p0 * a1 + p1 * c1);
  }
  uint4* dst = (uint4*)(wt + ((size_t)b * D + n) * D + k0);
#pragma unroll
  for (int q = 0; q < 4; ++q)
    dst[q] = make_uint4(r[4 * q], r[4 * q + 1], r[4 * q + 2], r[4 * q + 3]);
}

// ---------- kernel 3: out[b][s][o] = p0*bias[i0][o] + p1*bias[i1][o] (GEMM accumulates on top) ----------
__global__ void __launch_bounds__(256) init_out_kernel(const float* __restrict__ bias,
                                                       const int* __restrict__ sidx,
                                                       const float* __restrict__ sprob,
                                                       float* __restrict__ out) {
  const int b = blockIdx.y;
  const size_t t = (size_t)blockIdx.x * 256 + threadIdx.x;  // one float4
  const int o = (int)((t * 4) & (D - 1));
  const int i0 = sidx[2 * b], i1 = sidx[2 * b + 1];
  const float p0 = sprob[2 * b], p1 = sprob[2 * b + 1];
  const float4 b0 = *(const float4*)(bias + (size_t)i0 * D + o);
  const float4 b1 = *(const float4*)(bias + (size_t)i1 * D + o);
  float4 v = make_float4(p0 * b0.x + p1 * b1.x, p0 * b0.y + p1 * b1.y,
                         p0 * b0.z + p1 * b1.z, p0 * b0.w + p1 * b1.w);
  ((float4*)(out + (size_t)b * D * D))[t] = v;
}

// ---------- kernel 4: split-K GEMM, atomic-add epilogue ----------
// 128x128 tile, BK=32, 4 waves x (4x4) mfma_f32_16x16x32_bf16.
// grid (16, 16, BATCH*SPLITK) = 2048 blocks -> always-queued work per CU.
__global__ void __launch_bounds__(256) gemm_kernel(const u16* __restrict__ xb,
                                                   const u16* __restrict__ wt,
                                                   float* __restrict__ out) {
  __shared__ __align__(16) u16 As[128 * 32];  // As[r][k], row stride 32 bf16
  __shared__ __align__(16) u16 Bs[128 * 32];  // Bs[n][k]

  const int bz = blockIdx.z;
  const int b  = bz >> 2;          // batch
  const int ks = bz & 3;           // k-slice
  const int n0 = blockIdx.x * 128;
  const int m0 = blockIdx.y * 128;
  const int t = threadIdx.x;
  const int lane = t & 63;
  const int wm = ((t >> 6) & 1) * 64;
  const int wn = ((t >> 6) >> 1) * 64;

  const u16* Ab = xb + (size_t)b * D * D;
  const u16* Bb = wt + (size_t)b * D * D;

  const int r0 = t >> 2, c8 = (t & 3) * 8;
  const u16* gA0 = Ab + (size_t)(m0 + r0) * D + c8;
  const u16* gA1 = Ab + (size_t)(m0 + 64 + r0) * D + c8;
  const u16* gB0 = Bb + (size_t)(n0 + r0) * D + c8;
  const u16* gB1 = Bb + (size_t)(n0 + 64 + r0) * D + c8;
  u16* lA0 = As + (t & ~63) * 8;
  u16* lA1 = As + (256 + (t & ~63)) * 8;
  u16* lB0 = Bs + (t & ~63) * 8;
  u16* lB1 = Bs + (256 + (t & ~63)) * 8;

  const int fm = lane & 15;
  const int kh = (lane >> 4) * 8;

  f32x4 acc[4][4] = {};

  const int kbeg = ks * KSLICE, kend = kbeg + KSLICE;
  for (int k0 = kbeg; k0 < kend; k0 += 32) {
    async16(gA0 + k0, lA0);
    async16(gA1 + k0, lA1);
    async16(gB0 + k0, lB0);
    async16(gB1 + k0, lB1);
    __syncthreads();

    bf16x8 af[4], bfr[4];
#pragma unroll
    for (int i = 0; i < 4; ++i) {
      af[i]  = *(const bf16x8*)(As + (wm + i * 16 + fm) * 32 + kh);
      bfr[i] = *(const bf16x8*)(Bs + (wn + i * 16 + fm) * 32 + kh);
    }
#pragma unroll
    for (int i = 0; i < 4; ++i)
#pragma unroll
      for (int j = 0; j < 4; ++j)
        acc[i][j] = __builtin_amdgcn_mfma_f32_16x16x32_bf16(af[i], bfr[j], acc[i][j], 0, 0, 0);
    __syncthreads();
  }

  // epilogue: C/D layout col=lane&15, row=(lane>>4)*4+reg; device-scope f32 atomic add
  const int rq = (lane >> 4) * 4;
  float* Ob = out + (size_t)b * D * D;
#pragma unroll
  for (int j = 0; j < 4; ++j) {
    const int colg = n0 + wn + j * 16 + fm;
#pragma unroll
    for (int i = 0; i < 4; ++i) {
      const int rowb = m0 + wm + i * 16 + rq;
#pragma unroll
      for (int r = 0; r < 4; ++r)
        unsafeAtomicAdd(&Ob[(size_t)(rowb + r) * D + colg], acc[i][j][r]);
    }
  }
}

extern "C" void kernel_launch(void* const* d_in, const int* in_sizes, int n_in,
                              void* d_out, int out_size, void* d_ws, size_t ws_size,
                              hipStream_t stream) {
  const float* tensor = (const float*)d_in[0];   // (2,2048,16,128) fp32
  const int*   sidx   = (const int*)d_in[1];     // (2,2) int32
  const float* sprob  = (const float*)d_in[2];   // (2,2) fp32
  const float* weight = (const float*)d_in[3];   // (16,2048,2048) fp32
  const float* bias   = (const float*)d_in[4];   // (16,2048) fp32
  float* out = (float*)d_out;                    // (2,2048,2048) fp32

  u16* xb = (u16*)d_ws;                          // (2,2048,2048) bf16, 16 MB
  u16* wt = xb + (size_t)BATCH * D * D;          // (2,2048,2048) bf16, 16 MB

  hipLaunchKernelGGL(prep_x_kernel, dim3((BATCH * D * D) / (256 * 8)), dim3(256), 0, stream,
                     tensor, xb);
  hipLaunchKernelGGL(prep_w_kernel, dim3(D / 256, D / 32, BATCH), dim3(256), 0, stream,
                     weight, sidx, sprob, wt);
  hipLaunchKernelGGL(init_out_kernel, dim3((D * D) / (256 * 4), BATCH), dim3(256), 0, stream,
                     bias, sidx, sprob, out);
  hipLaunchKernelGGL(gemm_kernel, dim3(D / 128, D / 128, BATCH * SPLITK), dim3(256), 0, stream,
                     xb, wt, out);
}

// Round 3
// 387.169 us; speedup vs baseline: 1.2555x; 1.2555x over previous
//
#include <hip/hip_runtime.h>

typedef unsigned int u32;
typedef unsigned short u16;
typedef __bf16 bf16x8 __attribute__((ext_vector_type(8)));
typedef float f32x4 __attribute__((ext_vector_type(4)));

#define D 2048           // D_IN == D_MODEL == S == 2048
#define BATCH 2

// ---------- helpers ----------
__device__ __forceinline__ u32 bf16rne(float f) {
  u32 u = __builtin_bit_cast(u32, f);
  return (u + 0x7fffu + ((u >> 16) & 1u)) >> 16;
}
__device__ __forceinline__ u32 pk2(float lo, float hi) {
  return bf16rne(lo) | (bf16rne(hi) << 16);
}
__device__ __forceinline__ void async16(const u16* g, u16* l) {
  __builtin_amdgcn_global_load_lds(
      (const __attribute__((address_space(1))) void*)g,
      (__attribute__((address_space(3))) void*)l, 16, 0, 0);
}

// ---------- kernel 1: x fp32 -> bf16 ----------
__global__ void __launch_bounds__(256) prep_x_kernel(const float* __restrict__ x,
                                                     u16* __restrict__ o) {
  size_t t = (size_t)blockIdx.x * 256 + threadIdx.x;
  const float4* x4 = (const float4*)x;
  float4 a = x4[2 * t], b = x4[2 * t + 1];
  ((uint4*)o)[t] = make_uint4(pk2(a.x, a.y), pk2(a.z, a.w),
                              pk2(b.x, b.y), pk2(b.z, b.w));
}

// ---------- kernel 2: wt[b][n][k] = bf16(p0*W[i0][k][n] + p1*W[i1][k][n]) ----------
__global__ void __launch_bounds__(256) prep_w_kernel(const float* __restrict__ W,
                                                     const int* __restrict__ sidx,
                                                     const float* __restrict__ sprob,
                                                     u16* __restrict__ wt) {
  const int b = blockIdx.z;
  const int n = blockIdx.x * 256 + threadIdx.x;
  const int k0 = blockIdx.y * 32;
  const int i0 = sidx[2 * b], i1 = sidx[2 * b + 1];
  const float p0 = sprob[2 * b], p1 = sprob[2 * b + 1];
  const float* w0 = W + ((size_t)i0 * D + k0) * D + n;
  const float* w1 = W + ((size_t)i1 * D + k0) * D + n;
  u32 r[16];
#pragma unroll
  for (int kk = 0; kk < 16; ++kk) {
    float a0 = w0[(size_t)(2 * kk) * D],     c0 = w1[(size_t)(2 * kk) * D];
    float a1 = w0[(size_t)(2 * kk + 1) * D], c1 = w1[(size_t)(2 * kk + 1) * D];
    r[kk] = pk2(p0 * a0 + p1 * c0, p0 * a1 + p1 * c1);
  }
  uint4* dst = (uint4*)(wt + ((size_t)b * D + n) * D + k0);
#pragma unroll
  for (int q = 0; q < 4; ++q)
    dst[q] = make_uint4(r[4 * q], r[4 * q + 1], r[4 * q + 2], r[4 * q + 3]);
}

// ---------- kernel 3: out[b] = xb[b] @ wt[b]^T + bsel[b] ----------
// 128x128 tile, BK=64 as two stride-32 k-planes (conflict-free LDS, contiguous
// global_load_lds granules), 512 threads = 8 waves (4m x 2n), double-buffered LDS.
// Each wave: 32x64 sub-tile = 2x4 accumulators of mfma_f32_16x16x32_bf16.
__global__ void __launch_bounds__(512, 4) gemm_kernel(const u16* __restrict__ xb,
                                                      const u16* __restrict__ wt,
                                                      const float* __restrict__ bias,
                                                      const int* __restrict__ sidx,
                                                      const float* __restrict__ sprob,
                                                      float* __restrict__ out) {
  // [buf][plane: A-k0, A-k1, B-k0, B-k1][128 rows x 32 k] = 64 KB total
  __shared__ __align__(16) u16 L[2][4][128 * 32];

  const int b  = blockIdx.z;
  const int n0 = blockIdx.x * 128;
  const int m0 = blockIdx.y * 128;
  const int t = threadIdx.x;
  const int lane = t & 63;
  const int wid = t >> 6;
  const int wm = (wid & 3) * 32;   // wave m-offset (4 waves over 128 rows)
  const int wn = (wid >> 2) * 64;  // wave n-offset (2 waves over 128 cols)

  const u16* Ab = xb + (size_t)b * D * D;
  const u16* Bb = wt + (size_t)b * D * D;

  // staging: granule g = t; row r0 = t>>2 (covers all 128 rows), chunk c8 = (t&3)*8
  const int r0 = t >> 2, c8 = (t & 3) * 8;
  const u16* gA = Ab + (size_t)(m0 + r0) * D + c8;
  const u16* gB = Bb + (size_t)(n0 + r0) * D + c8;
  const int wbase = (t & ~63) * 8;  // wave-uniform LDS granule base (elements)

  const int fm = lane & 15;
  const int kh = (lane >> 4) * 8;

  f32x4 acc[2][4] = {};

  auto stage = [&](int buf, int k0) {
    async16(gA + k0,      &L[buf][0][wbase]);
    async16(gA + k0 + 32, &L[buf][1][wbase]);
    async16(gB + k0,      &L[buf][2][wbase]);
    async16(gB + k0 + 32, &L[buf][3][wbase]);
  };

  stage(0, 0);
  __syncthreads();

  for (int it = 0; it < D / 64; ++it) {
    const int cur = it & 1;
    if (it + 1 < D / 64) stage(cur ^ 1, (it + 1) * 64);  // prefetch next K-chunk

    bf16x8 af[2][2], bfr[4][2];
#pragma unroll
    for (int ks = 0; ks < 2; ++ks) {
#pragma unroll
      for (int i = 0; i < 2; ++i)
        af[i][ks]  = *(const bf16x8*)(&L[cur][ks][(wm + i * 16 + fm) * 32 + kh]);
#pragma unroll
      for (int j = 0; j < 4; ++j)
        bfr[j][ks] = *(const bf16x8*)(&L[cur][2 + ks][(wn + j * 16 + fm) * 32 + kh]);
    }
#pragma unroll
    for (int ks = 0; ks < 2; ++ks)
#pragma unroll
      for (int i = 0; i < 2; ++i)
#pragma unroll
        for (int j = 0; j < 4; ++j)
          acc[i][j] = __builtin_amdgcn_mfma_f32_16x16x32_bf16(af[i][ks], bfr[j][ks],
                                                              acc[i][j], 0, 0, 0);
    __syncthreads();  // drains prefetch vmcnt + frees cur for overwrite next iter
  }

  // epilogue: C/D layout col=lane&15, row=(lane>>4)*4+reg; fuse bias superposition
  const int i0 = sidx[2 * b], i1 = sidx[2 * b + 1];
  const float p0 = sprob[2 * b], p1 = sprob[2 * b + 1];
  const int rq = (lane >> 4) * 4;
  float* Ob = out + (size_t)b * D * D;
#pragma unroll
  for (int j = 0; j < 4; ++j) {
    const int colg = n0 + wn + j * 16 + fm;
    const float bs = p0 * bias[i0 * D + colg] + p1 * bias[i1 * D + colg];
#pragma unroll
    for (int i = 0; i < 2; ++i) {
      const int rowb = m0 + wm + i * 16 + rq;
#pragma unroll
      for (int r = 0; r < 4; ++r)
        Ob[(size_t)(rowb + r) * D + colg] = acc[i][j][r] + bs;
    }
  }
}

extern "C" void kernel_launch(void* const* d_in, const int* in_sizes, int n_in,
                              void* d_out, int out_size, void* d_ws, size_t ws_size,
                              hipStream_t stream) {
  const float* tensor = (const float*)d_in[0];   // (2,2048,16,128) fp32
  const int*   sidx   = (const int*)d_in[1];     // (2,2) int32
  const float* sprob  = (const float*)d_in[2];   // (2,2) fp32
  const float* weight = (const float*)d_in[3];   // (16,2048,2048) fp32
  const float* bias   = (const float*)d_in[4];   // (16,2048) fp32
  float* out = (float*)d_out;                    // (2,2048,2048) fp32

  u16* xb = (u16*)d_ws;                          // (2,2048,2048) bf16, 16 MB
  u16* wt = xb + (size_t)BATCH * D * D;          // (2,2048,2048) bf16, 16 MB

  hipLaunchKernelGGL(prep_x_kernel, dim3((BATCH * D * D) / (256 * 8)), dim3(256), 0, stream,
                     tensor, xb);
  hipLaunchKernelGGL(prep_w_kernel, dim3(D / 256, D / 32, BATCH), dim3(256), 0, stream,
                     weight, sidx, sprob, wt);
  hipLaunchKernelGGL(gemm_kernel, dim3(D / 128, D / 128, BATCH), dim3(512), 0, stream,
                     xb, wt, bias, sidx, sprob, out);
}